// Round 7
// baseline (663.039 us; speedup 1.0000x reference)
//
#include <hip/hip_runtime.h>
#include <cstdint>
#include <cstddef>

#define BB 2
#define SS 2048
#define EE 1024
#define HH 16
#define DH 64
#define KKSEL 409   // kk = int(2048*0.2)
#define QT 16       // query rows per attention block
#define PST 136     // probs LDS row stride (bf16 elems) per half (128 cols + pad)

typedef __attribute__((ext_vector_type(8))) short bf16x8;
typedef __attribute__((ext_vector_type(4))) float f32x4;
typedef unsigned short ushort_t;

__device__ __forceinline__ unsigned short f2bf(float f){
    unsigned u = __float_as_uint(f);
    u += 0x7fffu + ((u >> 16) & 1u);          // RNE
    return (unsigned short)(u >> 16);
}
__device__ __forceinline__ float bf2f(unsigned short h){
    return __uint_as_float(((unsigned)h) << 16);
}
__device__ __forceinline__ unsigned sortkey(float f){
    unsigned u = __float_as_uint(f);
    return (u & 0x80000000u) ? ~u : (u | 0x80000000u);
}
__device__ __forceinline__ float inv_sortkey(unsigned k){
    unsigned u = (k & 0x80000000u) ? (k & 0x7fffffffu) : ~k;
    return __uint_as_float(u);
}
__device__ __forceinline__ void split8(const float* f, bf16x8& h, bf16x8& l){
    #pragma unroll
    for (int j = 0; j < 8; ++j){
        ushort_t hh = f2bf(f[j]);
        h[j] = (short)hh;
        l[j] = (short)f2bf(f[j] - bf2f(hh));
    }
}
// async 16B/lane global->LDS; LDS dest = wave-uniform base + lane*16
__device__ __forceinline__ void gload_lds16(const ushort_t* g, ushort_t* l){
    __builtin_amdgcn_global_load_lds(
        (const __attribute__((address_space(1))) void*)g,
        (__attribute__((address_space(3))) void*)l, 16, 0, 0);
}

// ---------------------------------------------------------------------------
// convert_wt4: 4x fused. W (1024x1024 [k][n]) -> W^T bf16 hi/lo ([n][k])
// ---------------------------------------------------------------------------
struct CvtArgs {
    const float* W[4];
    ushort_t* H[4];
    ushort_t* L[4];
};

__global__ __launch_bounds__(256) void convert_wt4(CvtArgs a)
{
    __shared__ float T[64][65];
    const int z = blockIdx.z;
    const float* __restrict__ W = a.W[z];
    ushort_t* __restrict__ Ht = a.H[z];
    ushort_t* __restrict__ Lt = a.L[z];

    const int tid = threadIdx.x;
    const int ty = tid >> 4, tx = tid & 15;
    const int n0 = blockIdx.x * 64, k0 = blockIdx.y * 64;
    #pragma unroll
    for (int i = 0; i < 4; ++i){
        const int kl = ty + i * 16;
        float4 w = *(const float4*)&W[(size_t)(k0 + kl) * EE + n0 + tx * 4];
        T[kl][tx*4 + 0] = w.x; T[kl][tx*4 + 1] = w.y;
        T[kl][tx*4 + 2] = w.z; T[kl][tx*4 + 3] = w.w;
    }
    __syncthreads();
    #pragma unroll
    for (int i = 0; i < 4; ++i){
        const int nl = ty + i * 16;
        ushort4 h, l;
        ushort_t* hp = &h.x; ushort_t* lp = &l.x;
        #pragma unroll
        for (int j = 0; j < 4; ++j){
            const float v = T[tx*4 + j][nl];
            ushort_t hh = f2bf(v);
            hp[j] = hh;
            lp[j] = f2bf(v - bf2f(hh));
        }
        const size_t o = (size_t)(n0 + nl) * EE + k0 + tx * 4;
        *(ushort4*)&Ht[o] = h;
        *(ushort4*)&Lt[o] = l;
    }
}

// ---------------------------------------------------------------------------
// Split-bf16 MFMA GEMM body, 128(M) x 64(N) tile, 256 threads, single-buffered
// 24 KB LDS. Block coords (bx,by) passed in (caller applies the XCD-panel
// swizzle: each XCD owns 4 contiguous m-slabs and iterates n within them, so
// the 512 KB X slab stays L2-resident -> ~2.7x less L2/L3 traffic).
// X staged fp32->split-bf16 via registers; W hi/lo via async global_load_lds.
// Per-output-element MFMA chain order is unchanged -> bit-identical results.
// MODE 0: Q -> bf16 hi/lo [bh][s][d]   MODE 1: K -> hi, scaled by ts[h]
// MODE 2: V -> hi, transposed [bh][d][s]   MODE 3: fp32 row-major
// ---------------------------------------------------------------------------
template<int MODE>
__device__ __forceinline__ void gemm_body(
        const float* __restrict__ X,
        const ushort_t* __restrict__ Wth, const ushort_t* __restrict__ Wtl,
        const float* __restrict__ bias, const float* __restrict__ ts,
        float* __restrict__ OutF, ushort_t* __restrict__ OutH,
        ushort_t* __restrict__ OutL, ushort_t* buf, int bx, int by)
{
    const int tid  = threadIdx.x;
    const int lane = tid & 63, wave = tid >> 6;
    const int c16  = lane & 15, qd = lane >> 4;
    const int m0 = by * 128, n0 = bx * 64;
    const int wm = (wave >> 1) * 64, wn = (wave & 1) * 32;
    const int lrow = tid >> 1, lkg = (tid & 1) * 16;

    f32x4 acc[8];   // MODE2: [mfrag*2+nfrag]; else: [nfrag*4+mfrag]
    #pragma unroll
    for (int i = 0; i < 8; ++i) acc[i] = (f32x4){0.f,0.f,0.f,0.f};

    const float* Xr = X + (size_t)(m0 + lrow) * EE + lkg;

    // W async-staging source: wave stages rows [wave*16, wave*16+16) of the
    // 64-row W tile; lane covers row wave*16 + lane/4, k (lane&3)*8.
    const size_t wofs = (size_t)(n0 + wave*16 + (lane >> 2)) * EE + (lane & 3) * 8;
    const ushort_t* Wh = Wth + wofs;
    const ushort_t* Wl = Wtl + wofs;

    for (int k0 = 0; k0 < EE; k0 += 32){
        // ---- stage this k-slice ----
        gload_lds16(Wh + k0, buf + 8192  + wave*512);
        gload_lds16(Wl + k0, buf + 10240 + wave*512);
        {
            float fx[16];
            const float* xp = Xr + k0;
            *(float4*)&fx[0]  = *(const float4*)&xp[0];
            *(float4*)&fx[4]  = *(const float4*)&xp[4];
            *(float4*)&fx[8]  = *(const float4*)&xp[8];
            *(float4*)&fx[12] = *(const float4*)&xp[12];
            bf16x8 h0, l0, h1, l1;
            split8(fx, h0, l0); split8(fx + 8, h1, l1);
            *(bf16x8*)&buf[lrow*32 + lkg]           = h0;
            *(bf16x8*)&buf[lrow*32 + lkg + 8]       = h1;
            *(bf16x8*)&buf[4096 + lrow*32 + lkg]    = l0;
            *(bf16x8*)&buf[4096 + lrow*32 + lkg+8]  = l1;
        }
        __syncthreads();   // drains lgkm (X ds_writes) + vmcnt (W async)

        // ---- fragments + MFMA ----
        const ushort_t* A0 = buf;
        const ushort_t* A1 = buf + 4096;
        const ushort_t* B0 = buf + 8192;
        const ushort_t* B1 = buf + 10240;
        bf16x8 afh[4], afl[4], bfh[2], bfl[2];
        #pragma unroll
        for (int i = 0; i < 4; ++i){
            afh[i] = *(const bf16x8*)&A0[(wm + i*16 + c16)*32 + qd*8];
            afl[i] = *(const bf16x8*)&A1[(wm + i*16 + c16)*32 + qd*8];
        }
        #pragma unroll
        for (int j = 0; j < 2; ++j){
            bfh[j] = *(const bf16x8*)&B0[(wn + j*16 + c16)*32 + qd*8];
            bfl[j] = *(const bf16x8*)&B1[(wn + j*16 + c16)*32 + qd*8];
        }
        if (MODE == 2){   // X first: D rows <- s
            #pragma unroll
            for (int ma = 0; ma < 4; ++ma){
                #pragma unroll
                for (int nb = 0; nb < 2; ++nb){
                    const int id = ma*2 + nb;
                    acc[id] = __builtin_amdgcn_mfma_f32_16x16x32_bf16(afh[ma], bfh[nb], acc[id], 0,0,0);
                    acc[id] = __builtin_amdgcn_mfma_f32_16x16x32_bf16(afh[ma], bfl[nb], acc[id], 0,0,0);
                    acc[id] = __builtin_amdgcn_mfma_f32_16x16x32_bf16(afl[ma], bfh[nb], acc[id], 0,0,0);
                }
            }
        } else {          // W first: D rows <- n
            #pragma unroll
            for (int na = 0; na < 2; ++na){
                #pragma unroll
                for (int mb = 0; mb < 4; ++mb){
                    const int id = na*4 + mb;
                    acc[id] = __builtin_amdgcn_mfma_f32_16x16x32_bf16(bfh[na], afh[mb], acc[id], 0,0,0);
                    acc[id] = __builtin_amdgcn_mfma_f32_16x16x32_bf16(bfh[na], afl[mb], acc[id], 0,0,0);
                    acc[id] = __builtin_amdgcn_mfma_f32_16x16x32_bf16(bfl[na], afh[mb], acc[id], 0,0,0);
                }
            }
        }
        if (k0 + 32 < EE) __syncthreads();   // buffer reuse guard
    }

    if (MODE == 3){
        #pragma unroll
        for (int na = 0; na < 2; ++na){
            const int ng = n0 + wn + na*16 + qd*4;
            float4 b4 = *(const float4*)&bias[ng];
            const float bb[4] = {b4.x, b4.y, b4.z, b4.w};
            #pragma unroll
            for (int mb = 0; mb < 4; ++mb){
                const int mg = m0 + wm + mb*16 + c16;
                const f32x4 av = acc[na*4 + mb];
                float4 o;
                o.x = av[0] + bb[0]; o.y = av[1] + bb[1];
                o.z = av[2] + bb[2]; o.w = av[3] + bb[3];
                *(float4*)&OutF[(size_t)mg * EE + ng] = o;
            }
        }
    } else if (MODE == 0){
        #pragma unroll
        for (int na = 0; na < 2; ++na){
            const int ng = n0 + wn + na*16 + qd*4;
            const int h = ng >> 6, d0 = ng & 63;
            float4 b4 = *(const float4*)&bias[ng];
            const float bb[4] = {b4.x, b4.y, b4.z, b4.w};
            #pragma unroll
            for (int mb = 0; mb < 4; ++mb){
                const int mg = m0 + wm + mb*16 + c16;
                const int bi = mg >> 11, s = mg & (SS - 1);
                const f32x4 av = acc[na*4 + mb];
                ushort4 hv, lv;
                ushort_t* hp = &hv.x; ushort_t* lp = &lv.x;
                #pragma unroll
                for (int r = 0; r < 4; ++r){
                    const float v = av[r] + bb[r];
                    ushort_t hh = f2bf(v);
                    hp[r] = hh;
                    lp[r] = f2bf(v - bf2f(hh));
                }
                const size_t o = (((size_t)(bi * HH + h)) * SS + s) * DH + d0;
                *(ushort4*)&OutH[o] = hv;
                *(ushort4*)&OutL[o] = lv;
            }
        }
    } else if (MODE == 1){
        #pragma unroll
        for (int na = 0; na < 2; ++na){
            const int ng = n0 + wn + na*16 + qd*4;
            const int h = ng >> 6, d0 = ng & 63;
            const float tsc = ts[h];
            float4 b4 = *(const float4*)&bias[ng];
            const float bb[4] = {b4.x, b4.y, b4.z, b4.w};
            #pragma unroll
            for (int mb = 0; mb < 4; ++mb){
                const int mg = m0 + wm + mb*16 + c16;
                const int bi = mg >> 11, s = mg & (SS - 1);
                const f32x4 av = acc[na*4 + mb];
                ushort4 hv;
                ushort_t* hp = &hv.x;
                #pragma unroll
                for (int r = 0; r < 4; ++r)
                    hp[r] = f2bf((av[r] + bb[r]) * tsc);
                *(ushort4*)&OutH[(((size_t)(bi * HH + h)) * SS + s) * DH + d0] = hv;
            }
        }
    } else { // MODE 2: V^T hi only
        #pragma unroll
        for (int ma = 0; ma < 4; ++ma){
            const int mg = m0 + wm + ma*16 + qd*4;
            const int bi = mg >> 11, s0 = mg & (SS - 1);
            #pragma unroll
            for (int nb = 0; nb < 2; ++nb){
                const int ng = n0 + wn + nb*16 + c16;
                const int h = ng >> 6, d = ng & 63;
                const float bv = bias[ng];
                const f32x4 av = acc[ma*2 + nb];
                ushort4 hv;
                ushort_t* hp = &hv.x;
                #pragma unroll
                for (int r = 0; r < 4; ++r) hp[r] = f2bf(av[r] + bv);
                *(ushort4*)&OutH[(((size_t)(bi * HH + h)) * DH + d) * SS + s0] = hv;
            }
        }
    }
}

// XCD-panel swizzle: HW dispatches blocks round-robin across 8 XCDs by
// linear id. Remap so XCD c owns m-slabs [4c,4c+4) and iterates n fastest:
// the X slab (512 KB) then stays in c's L2 across 16 consecutive blocks.
// Bijective for nwg=512 (16n x 32m). z handled outside (512 % 8 == 0).
__device__ __forceinline__ void panel_swizzle(int& bx, int& by){
    const int lin = blockIdx.x + 16 * blockIdx.y;   // 0..511
    const int xcd = lin & 7, idx = lin >> 3;        // idx 0..63
    bx = idx & 15;
    by = (xcd << 2) | (idx >> 4);
}

// Fused Q/K/V projections: blockIdx.z picks the problem. 1536 blocks.
__global__ __launch_bounds__(256) void gemm_qkv(
        const float* __restrict__ q, const float* __restrict__ k,
        const float* __restrict__ v,
        const ushort_t* __restrict__ Wqh, const ushort_t* __restrict__ Wql,
        const ushort_t* __restrict__ Wkh, const ushort_t* __restrict__ Wkl,
        const ushort_t* __restrict__ Wvh, const ushort_t* __restrict__ Wvl,
        const float* __restrict__ bq, const float* __restrict__ bk,
        const float* __restrict__ bv, const float* __restrict__ ts,
        ushort_t* __restrict__ Qh, ushort_t* __restrict__ Ql,
        ushort_t* __restrict__ Kh, ushort_t* __restrict__ Vth)
{
    __shared__ ushort_t buf[12288];   // 24 KB
    int bx, by;
    panel_swizzle(bx, by);
    const int z = blockIdx.z;
    if (z == 0)
        gemm_body<0>(q, Wqh, Wql, bq, nullptr, nullptr, Qh, Ql, buf, bx, by);
    else if (z == 1)
        gemm_body<1>(k, Wkh, Wkl, bk, ts, nullptr, Kh, nullptr, buf, bx, by);
    else
        gemm_body<2>(v, Wvh, Wvl, bv, nullptr, nullptr, Vth, nullptr, buf, bx, by);
}

__global__ __launch_bounds__(256) void gemm_out(
        const float* __restrict__ X,
        const ushort_t* __restrict__ Wth, const ushort_t* __restrict__ Wtl,
        const float* __restrict__ bias, float* __restrict__ OutF)
{
    __shared__ ushort_t buf[12288];
    int bx, by;
    panel_swizzle(bx, by);
    gemm_body<3>(X, Wth, Wtl, bias, nullptr, OutF, nullptr, nullptr, buf, bx, by);
}

// ---------------------------------------------------------------------------
// Fused attention (R6-proven structure). 512 threads / 8 waves; wave owns 256
// score columns. Top-k threshold: LDS exchange so each wave owns full rows,
// then integer bisection with the bracket initialized from the row's measured
// min/max keys (in-register + shuffle reduce) instead of the fixed [-64,64]
// span: ~2x fewer serial iterations, identical per-iteration code, identical
// invariant (cnt(lo)>=K>cnt(hi)) and early-exit semantics -> exact.
// ---------------------------------------------------------------------------
__global__ __launch_bounds__(512, 4) void attn_kernel(
        const ushort_t* __restrict__ Qh, const ushort_t* __restrict__ Ql,
        const ushort_t* __restrict__ Khi, const ushort_t* __restrict__ Vth,
        float* __restrict__ AO)
{
    __shared__ __align__(16) char uni[65536];
    __shared__ float wsums[8][16];
    __shared__ unsigned thr16[16];

    const int tid  = threadIdx.x;
    const int lane = tid & 63;
    const int wave = tid >> 6;
    const int qd   = lane >> 4;
    const int c16  = lane & 15;
    const unsigned Bx = blockIdx.x;
    const int xcd  = Bx & 7;
    const int qq   = Bx >> 3;
    const int tile = qq & 127;
    const int bh   = (qq >> 7) * 8 + xcd;
    const int t0   = tile * QT;
    const int wbase = wave * 256;

    // ---- Q fragments (pre-split hi/lo) ----
    bf16x8 qh[2], ql[2];
    {
        const size_t qbase = ((size_t)bh * SS + t0 + c16) * DH;
        #pragma unroll
        for (int kc = 0; kc < 2; ++kc){
            qh[kc] = *(const bf16x8*)&Qh[qbase + kc*32 + qd*8];
            ql[kc] = *(const bf16x8*)&Ql[qbase + kc*32 + qd*8];
        }
    }

    // ---- phase 1: scores (K hi-only, Q split) ----
    f32x4 acc[16];
    const ushort_t* Kh = Khi + (size_t)bh * SS * DH;
    #pragma unroll
    for (int t = 0; t < 16; ++t){
        f32x4 a = {0.f, 0.f, 0.f, 0.f};
        const int srow = wbase + t*16 + c16;
        const ushort_t* kp = Kh + (size_t)srow * DH + qd*8;
        #pragma unroll
        for (int kc = 0; kc < 2; ++kc){
            bf16x8 kh = *(const bf16x8*)(kp + kc*32);
            a = __builtin_amdgcn_mfma_f32_16x16x32_bf16(qh[kc], kh, a, 0, 0, 0);
            a = __builtin_amdgcn_mfma_f32_16x16x32_bf16(ql[kc], kh, a, 0, 0, 0);
        }
        acc[t] = a;
    }

    // ---- scale + diag boost, to sortkeys in place ----
    #pragma unroll
    for (int t = 0; t < 16; ++t){
        const int colg = wbase + t*16 + c16;
        #pragma unroll
        for (int r = 0; r < 4; ++r){
            float v = acc[t][r] * 0.15625f;        // 1/8 * 1.25
            if (colg == t0 + qd*4 + r) v *= 1.15f;
            acc[t][r] = __uint_as_float(sortkey(v));
        }
    }

    // ---- phase 2: exact top-k threshold (exchange + bisection) ----
    float* ex = (float*)uni;   // 8 rows x 2048 fp32 (key bits)
    #pragma unroll
    for (int half = 0; half < 2; ++half){
        if ((qd >> 1) == half){
            const int rl = (qd & 1) * 4;
            #pragma unroll
            for (int t = 0; t < 16; ++t)
                #pragma unroll
                for (int r = 0; r < 4; ++r)
                    ex[(rl + r) * SS + wbase + t*16 + c16] = acc[t][r];
        }
        __syncthreads();
        unsigned cand[32];
        #pragma unroll
        for (int j = 0; j < 32; ++j)
            cand[j] = __float_as_uint(ex[wave * SS + lane + 64*j]);
        // measured bracket: min/max key over the row (sortkey is monotone)
        unsigned kmn = cand[0], kmx = cand[0];
        #pragma unroll
        for (int j = 1; j < 32; ++j){
            kmn = (cand[j] < kmn) ? cand[j] : kmn;
            kmx = (cand[j] > kmx) ? cand[j] : kmx;
        }
        #pragma unroll
        for (int off = 1; off < 64; off <<= 1){
            const unsigned on = (unsigned)__shfl_xor((int)kmn, off, 64);
            const unsigned ox = (unsigned)__shfl_xor((int)kmx, off, 64);
            kmn = (on < kmn) ? on : kmn;
            kmx = (ox > kmx) ? ox : kmx;
        }
        unsigned lo = kmn, hi = kmx + 1u;   // cnt(lo)=2048>=K, cnt(hi)=0<K
        #pragma unroll 1
        for (int it = 0; it < 32 && (hi - lo) > 1u; ++it){
            const unsigned mid = lo + ((hi - lo) >> 1);
            int c = 0;
            #pragma unroll
            for (int j = 0; j < 32; ++j){
                int pc;
                asm("v_cmp_le_u32 vcc, %1, %2\n\t"
                    "s_bcnt1_i32_b64 %0, vcc"
                    : "=s"(pc) : "s"(mid), "v"(cand[j]) : "vcc");
                c += pc;
            }
            if (c == KKSEL){ lo = mid; break; }
            if (c > KKSEL) lo = mid; else hi = mid;
        }
        if (lane == 0) thr16[half*8 + wave] = lo;
        __syncthreads();
    }

    // ---- phase 3: boost + exp + row sums ----
    unsigned thr[4];
    #pragma unroll
    for (int r = 0; r < 4; ++r) thr[r] = thr16[qd*4 + r];
    float psum[4] = {0.f, 0.f, 0.f, 0.f};
    #pragma unroll
    for (int t = 0; t < 16; ++t){
        #pragma unroll
        for (int r = 0; r < 4; ++r){
            const unsigned key = __float_as_uint(acc[t][r]);
            float s = inv_sortkey(key);
            s *= (key >= thr[r]) ? 1.15f : 1.0f;
            const float e = __expf(s);
            acc[t][r] = e;
            psum[r] += e;
        }
    }
    #pragma unroll
    for (int off = 1; off <= 8; off <<= 1){
        #pragma unroll
        for (int r = 0; r < 4; ++r) psum[r] += __shfl_xor(psum[r], off, 64);
    }
    if (c16 == 0){
        #pragma unroll
        for (int r = 0; r < 4; ++r) wsums[wave][qd*4 + r] = psum[r];
    }
    __syncthreads();
    float pinv[4];
    #pragma unroll
    for (int r = 0; r < 4; ++r){
        const int row = qd*4 + r;
        float s = 0.f;
        #pragma unroll
        for (int w = 0; w < 8; ++w) s += wsums[w][row];
        pinv[r] = 1.f / s;
    }

    // ---- phase 4: O = P @ V (two 128-col halves per wave) ----
    const ushort_t* Vh = Vth + (size_t)bh * DH * SS;
    ushort_t* pw = (ushort_t*)uni + wave * (QT * PST);   // per-wave region
    f32x4 oacc[4];
    #pragma unroll
    for (int dt = 0; dt < 4; ++dt) oacc[dt] = (f32x4){0.f, 0.f, 0.f, 0.f};

    #pragma unroll
    for (int half = 0; half < 2; ++half){
        #pragma unroll
        for (int tt = 0; tt < 8; ++tt){
            const int t = half*8 + tt;
            #pragma unroll
            for (int r = 0; r < 4; ++r)
                pw[(qd*4 + r) * PST + tt*16 + c16] = f2bf(acc[t][r] * pinv[r]);
        }
        // per-wave region: same-wave ds_write -> ds_read, no barrier needed
        #pragma unroll
        for (int kc = 0; kc < 4; ++kc){
            bf16x8 pf = *(const bf16x8*)&pw[c16 * PST + kc*32 + qd*8];
            const int sbase = wbase + half*128 + kc*32 + qd*8;
            #pragma unroll
            for (int dt = 0; dt < 4; ++dt){
                const int d = dt*16 + c16;
                bf16x8 vh = *(const bf16x8*)(Vh + (size_t)d * SS + sbase);
                oacc[dt] = __builtin_amdgcn_mfma_f32_16x16x32_bf16(pf, vh, oacc[dt], 0, 0, 0);
            }
        }
    }

    // ---- cross-wave O reduction + fp32 store ----
    __syncthreads();   // all probs reads done before red overwrites the union
    float* red = (float*)uni;   // 8 x 16 x 65
    #pragma unroll
    for (int dt = 0; dt < 4; ++dt)
        #pragma unroll
        for (int r = 0; r < 4; ++r)
            red[(wave*16 + qd*4 + r) * 65 + dt*16 + c16] = oacc[dt][r];
    __syncthreads();

    const int b = bh >> 4, h = bh & 15;
    {
        const int r  = tid >> 5;           // 0..15
        const int c2 = (tid & 31) * 2;     // 0,2,..,62
        float s0 = 0.f, s1 = 0.f;
        #pragma unroll
        for (int w = 0; w < 8; ++w){
            s0 += red[(w*16 + r) * 65 + c2];
            s1 += red[(w*16 + r) * 65 + c2 + 1];
        }
        float2 o; o.x = s0; o.y = s1;
        *(float2*)&AO[((size_t)b * SS + t0 + r) * EE + h*DH + c2] = o;
    }
}

// ---------------------------------------------------------------------------
extern "C" void kernel_launch(void* const* d_in, const int* in_sizes, int n_in,
                              void* d_out, int out_size, void* d_ws, size_t ws_size,
                              hipStream_t stream)
{
    const float* query = (const float*)d_in[0];
    const float* key   = (const float*)d_in[1];
    const float* value = (const float*)d_in[2];
    const float* Wq    = (const float*)d_in[3];
    const float* bq    = (const float*)d_in[4];
    const float* Wk    = (const float*)d_in[5];
    const float* bk    = (const float*)d_in[6];
    const float* Wv    = (const float*)d_in[7];
    const float* bv    = (const float*)d_in[8];
    const float* Wo    = (const float*)d_in[9];
    const float* bo    = (const float*)d_in[10];
    const float* ts    = (const float*)d_in[11];
    float* out = (float*)d_out;
    char* w = (char*)d_ws;

    const size_t MB = 1u << 20;
    ushort_t* Qh  = (ushort_t*)(w + 0 * MB);
    ushort_t* Ql  = (ushort_t*)(w + 8 * MB);
    ushort_t* Kh  = (ushort_t*)(w + 16 * MB);
    ushort_t* Vth = (ushort_t*)(w + 24 * MB);
    float*    AOw = (float*)   (w + 32 * MB);   // 16 MB fp32 (written by attn)
    // QKV converted weights live inside the AOw region: fully consumed by
    // gemm_qkv before attn writes AOw (stream-ordered).
    ushort_t* Wqh = (ushort_t*)(w + 32 * MB);
    ushort_t* Wql = (ushort_t*)(w + 34 * MB);
    ushort_t* Wkh = (ushort_t*)(w + 36 * MB);
    ushort_t* Wkl = (ushort_t*)(w + 38 * MB);
    ushort_t* Wvh = (ushort_t*)(w + 40 * MB);
    ushort_t* Wvl = (ushort_t*)(w + 42 * MB);
    ushort_t* Woh = (ushort_t*)(w + 48 * MB);
    ushort_t* Wol = (ushort_t*)(w + 50 * MB);

    CvtArgs ca;
    ca.W[0] = Wq;  ca.W[1] = Wk;  ca.W[2] = Wv;  ca.W[3] = Wo;
    ca.H[0] = Wqh; ca.H[1] = Wkh; ca.H[2] = Wvh; ca.H[3] = Woh;
    ca.L[0] = Wql; ca.L[1] = Wkl; ca.L[2] = Wvl; ca.L[3] = Wol;

    hipLaunchKernelGGL(convert_wt4, dim3(16, 16, 4), dim3(256), 0, stream, ca);
    // 128x64 tiles: N/64 x M/128 x 3 = 16 x 32 x 3 = 1536 blocks
    hipLaunchKernelGGL(gemm_qkv, dim3(16, 32, 3), dim3(256), 0, stream,
                       query, key, value, Wqh, Wql, Wkh, Wkl, Wvh, Wvl,
                       bq, bk, bv, ts, Qh, Ql, Kh, Vth);
    hipLaunchKernelGGL(attn_kernel, dim3(BB * HH * (SS / QT)), dim3(512), 0, stream,
                       Qh, Ql, Kh, Vth, AOw);
    // 16 x 32 = 512 blocks
    hipLaunchKernelGGL(gemm_out, dim3(16, 32), dim3(256), 0, stream,
                       AOw, Woh, Wol, bo, out);
}

// Round 8
// 641.846 us; speedup vs baseline: 1.0330x; 1.0330x over previous
//
#include <hip/hip_runtime.h>
#include <cstdint>
#include <cstddef>

#define BB 2
#define SS 2048
#define EE 1024
#define HH 16
#define DH 64
#define KKSEL 409   // kk = int(2048*0.2)
#define QT 16       // query rows per attention block
#define PST 136     // probs LDS row stride (bf16 elems) per half (128 cols + pad)

typedef __attribute__((ext_vector_type(8))) short bf16x8;
typedef __attribute__((ext_vector_type(4))) float f32x4;
typedef unsigned short ushort_t;

__device__ __forceinline__ unsigned short f2bf(float f){
    unsigned u = __float_as_uint(f);
    u += 0x7fffu + ((u >> 16) & 1u);          // RNE
    return (unsigned short)(u >> 16);
}
__device__ __forceinline__ float bf2f(unsigned short h){
    return __uint_as_float(((unsigned)h) << 16);
}
__device__ __forceinline__ unsigned sortkey(float f){
    unsigned u = __float_as_uint(f);
    return (u & 0x80000000u) ? ~u : (u | 0x80000000u);
}
__device__ __forceinline__ float inv_sortkey(unsigned k){
    unsigned u = (k & 0x80000000u) ? (k & 0x7fffffffu) : ~k;
    return __uint_as_float(u);
}
__device__ __forceinline__ void split8(const float* f, bf16x8& h, bf16x8& l){
    #pragma unroll
    for (int j = 0; j < 8; ++j){
        ushort_t hh = f2bf(f[j]);
        h[j] = (short)hh;
        l[j] = (short)f2bf(f[j] - bf2f(hh));
    }
}
// async 16B/lane global->LDS; LDS dest = wave-uniform base + lane*16
__device__ __forceinline__ void gload_lds16(const ushort_t* g, ushort_t* l){
    __builtin_amdgcn_global_load_lds(
        (const __attribute__((address_space(1))) void*)g,
        (__attribute__((address_space(3))) void*)l, 16, 0, 0);
}

// ---------------------------------------------------------------------------
// convert_wt4: 4x fused. W (1024x1024 [k][n]) -> W^T bf16 hi/lo ([n][k])
// ---------------------------------------------------------------------------
struct CvtArgs {
    const float* W[4];
    ushort_t* H[4];
    ushort_t* L[4];
};

__global__ __launch_bounds__(256) void convert_wt4(CvtArgs a)
{
    __shared__ float T[64][65];
    const int z = blockIdx.z;
    const float* __restrict__ W = a.W[z];
    ushort_t* __restrict__ Ht = a.H[z];
    ushort_t* __restrict__ Lt = a.L[z];

    const int tid = threadIdx.x;
    const int ty = tid >> 4, tx = tid & 15;
    const int n0 = blockIdx.x * 64, k0 = blockIdx.y * 64;
    #pragma unroll
    for (int i = 0; i < 4; ++i){
        const int kl = ty + i * 16;
        float4 w = *(const float4*)&W[(size_t)(k0 + kl) * EE + n0 + tx * 4];
        T[kl][tx*4 + 0] = w.x; T[kl][tx*4 + 1] = w.y;
        T[kl][tx*4 + 2] = w.z; T[kl][tx*4 + 3] = w.w;
    }
    __syncthreads();
    #pragma unroll
    for (int i = 0; i < 4; ++i){
        const int nl = ty + i * 16;
        ushort4 h, l;
        ushort_t* hp = &h.x; ushort_t* lp = &l.x;
        #pragma unroll
        for (int j = 0; j < 4; ++j){
            const float v = T[tx*4 + j][nl];
            ushort_t hh = f2bf(v);
            hp[j] = hh;
            lp[j] = f2bf(v - bf2f(hh));
        }
        const size_t o = (size_t)(n0 + nl) * EE + k0 + tx * 4;
        *(ushort4*)&Ht[o] = h;
        *(ushort4*)&Lt[o] = l;
    }
}

// ---------------------------------------------------------------------------
// convert_x3: activations (4096x1024 fp32) -> split bf16 hi/lo, row-major.
// Hoists the fp32->split conversion out of the GEMM k-loops entirely.
// ---------------------------------------------------------------------------
struct CvtX {
    const float* X[3];
    ushort_t* H[3];
    ushort_t* L[3];
};

__global__ __launch_bounds__(256) void convert_x3(CvtX a)
{
    const int z = blockIdx.z;
    const float* __restrict__ X = a.X[z];
    ushort_t* __restrict__ Hd = a.H[z];
    ushort_t* __restrict__ Ld = a.L[z];
    const size_t i = ((size_t)blockIdx.x * 256 + threadIdx.x) * 8;
    float fx[8];
    *(float4*)&fx[0] = *(const float4*)&X[i];
    *(float4*)&fx[4] = *(const float4*)&X[i + 4];
    bf16x8 h, l;
    split8(fx, h, l);
    *(bf16x8*)&Hd[i] = h;
    *(bf16x8*)&Ld[i] = l;
}

// ---------------------------------------------------------------------------
// Split-bf16 MFMA GEMM body, 128(M) x 64(N) tile, 256 threads, single-buffered
// 24 KB LDS (R6 structure: ~4-6 blocks/CU co-resident) with ALL operands
// pre-split bf16 in global and staged via async global_load_lds (6 per wave
// per k-step) -> zero conversion VALU in the hot loop. LDS layout is the
// linear [row][k] form byte-identical to R6's, so fragment reads and MFMA
// order are unchanged -> bit-identical results.
// MODE 0: Q -> bf16 hi/lo [bh][s][d]   MODE 1: K -> hi, scaled by ts[h]
// MODE 2: V -> hi, transposed [bh][d][s]   MODE 3: fp32 row-major
// ---------------------------------------------------------------------------
template<int MODE>
__device__ __forceinline__ void gemm_body(
        const ushort_t* __restrict__ Xh, const ushort_t* __restrict__ Xl,
        const ushort_t* __restrict__ Wth, const ushort_t* __restrict__ Wtl,
        const float* __restrict__ bias, const float* __restrict__ ts,
        float* __restrict__ OutF, ushort_t* __restrict__ OutH,
        ushort_t* __restrict__ OutL, ushort_t* buf, int bx, int by)
{
    const int tid  = threadIdx.x;
    const int lane = tid & 63, wave = tid >> 6;
    const int c16  = lane & 15, qd = lane >> 4;
    const int m0 = by * 128, n0 = bx * 64;
    const int wm = (wave >> 1) * 64, wn = (wave & 1) * 32;

    f32x4 acc[8];   // MODE2: [mfrag*2+nfrag]; else: [nfrag*4+mfrag]
    #pragma unroll
    for (int i = 0; i < 8; ++i) acc[i] = (f32x4){0.f,0.f,0.f,0.f};

    // async staging sources. X: wave owns 16-row segs seg0/seg1 of the 128-row
    // tile; lane covers row seg*16 + lane/4, k (lane&3)*8 -> LDS addr row*32+k.
    const int seg0 = wave * 2, seg1 = seg0 + 1;
    const int rl = lane >> 2, kl = (lane & 3) * 8;
    const size_t xofs0 = (size_t)(m0 + seg0*16 + rl) * EE + kl;
    const size_t xofs1 = (size_t)(m0 + seg1*16 + rl) * EE + kl;
    // W: wave stages rows [wave*16, wave*16+16) of the 64-row W tile.
    const size_t wofs = (size_t)(n0 + wave*16 + rl) * EE + kl;

    for (int k0 = 0; k0 < EE; k0 += 32){
        // ---- stage this k-slice (all async, no VALU) ----
        gload_lds16(Xh  + xofs0 + k0, buf +         seg0*512);
        gload_lds16(Xh  + xofs1 + k0, buf +         seg1*512);
        gload_lds16(Xl  + xofs0 + k0, buf + 4096  + seg0*512);
        gload_lds16(Xl  + xofs1 + k0, buf + 4096  + seg1*512);
        gload_lds16(Wth + wofs  + k0, buf + 8192  + wave*512);
        gload_lds16(Wtl + wofs  + k0, buf + 10240 + wave*512);
        __syncthreads();   // drains vmcnt (async stages)

        // ---- fragments + MFMA ----
        const ushort_t* A0 = buf;
        const ushort_t* A1 = buf + 4096;
        const ushort_t* B0 = buf + 8192;
        const ushort_t* B1 = buf + 10240;
        bf16x8 afh[4], afl[4], bfh[2], bfl[2];
        #pragma unroll
        for (int i = 0; i < 4; ++i){
            afh[i] = *(const bf16x8*)&A0[(wm + i*16 + c16)*32 + qd*8];
            afl[i] = *(const bf16x8*)&A1[(wm + i*16 + c16)*32 + qd*8];
        }
        #pragma unroll
        for (int j = 0; j < 2; ++j){
            bfh[j] = *(const bf16x8*)&B0[(wn + j*16 + c16)*32 + qd*8];
            bfl[j] = *(const bf16x8*)&B1[(wn + j*16 + c16)*32 + qd*8];
        }
        if (MODE == 2){   // X first: D rows <- s
            #pragma unroll
            for (int ma = 0; ma < 4; ++ma){
                #pragma unroll
                for (int nb = 0; nb < 2; ++nb){
                    const int id = ma*2 + nb;
                    acc[id] = __builtin_amdgcn_mfma_f32_16x16x32_bf16(afh[ma], bfh[nb], acc[id], 0,0,0);
                    acc[id] = __builtin_amdgcn_mfma_f32_16x16x32_bf16(afh[ma], bfl[nb], acc[id], 0,0,0);
                    acc[id] = __builtin_amdgcn_mfma_f32_16x16x32_bf16(afl[ma], bfh[nb], acc[id], 0,0,0);
                }
            }
        } else {          // W first: D rows <- n
            #pragma unroll
            for (int na = 0; na < 2; ++na){
                #pragma unroll
                for (int mb = 0; mb < 4; ++mb){
                    const int id = na*4 + mb;
                    acc[id] = __builtin_amdgcn_mfma_f32_16x16x32_bf16(bfh[na], afh[mb], acc[id], 0,0,0);
                    acc[id] = __builtin_amdgcn_mfma_f32_16x16x32_bf16(bfh[na], afl[mb], acc[id], 0,0,0);
                    acc[id] = __builtin_amdgcn_mfma_f32_16x16x32_bf16(bfl[na], afh[mb], acc[id], 0,0,0);
                }
            }
        }
        if (k0 + 32 < EE) __syncthreads();   // buffer reuse guard
    }

    if (MODE == 3){
        #pragma unroll
        for (int na = 0; na < 2; ++na){
            const int ng = n0 + wn + na*16 + qd*4;
            float4 b4 = *(const float4*)&bias[ng];
            const float bb[4] = {b4.x, b4.y, b4.z, b4.w};
            #pragma unroll
            for (int mb = 0; mb < 4; ++mb){
                const int mg = m0 + wm + mb*16 + c16;
                const f32x4 av = acc[na*4 + mb];
                float4 o;
                o.x = av[0] + bb[0]; o.y = av[1] + bb[1];
                o.z = av[2] + bb[2]; o.w = av[3] + bb[3];
                *(float4*)&OutF[(size_t)mg * EE + ng] = o;
            }
        }
    } else if (MODE == 0){
        #pragma unroll
        for (int na = 0; na < 2; ++na){
            const int ng = n0 + wn + na*16 + qd*4;
            const int h = ng >> 6, d0 = ng & 63;
            float4 b4 = *(const float4*)&bias[ng];
            const float bb[4] = {b4.x, b4.y, b4.z, b4.w};
            #pragma unroll
            for (int mb = 0; mb < 4; ++mb){
                const int mg = m0 + wm + mb*16 + c16;
                const int bi = mg >> 11, s = mg & (SS - 1);
                const f32x4 av = acc[na*4 + mb];
                ushort4 hv, lv;
                ushort_t* hp = &hv.x; ushort_t* lp = &lv.x;
                #pragma unroll
                for (int r = 0; r < 4; ++r){
                    const float v = av[r] + bb[r];
                    ushort_t hh = f2bf(v);
                    hp[r] = hh;
                    lp[r] = f2bf(v - bf2f(hh));
                }
                const size_t o = (((size_t)(bi * HH + h)) * SS + s) * DH + d0;
                *(ushort4*)&OutH[o] = hv;
                *(ushort4*)&OutL[o] = lv;
            }
        }
    } else if (MODE == 1){
        #pragma unroll
        for (int na = 0; na < 2; ++na){
            const int ng = n0 + wn + na*16 + qd*4;
            const int h = ng >> 6, d0 = ng & 63;
            const float tsc = ts[h];
            float4 b4 = *(const float4*)&bias[ng];
            const float bb[4] = {b4.x, b4.y, b4.z, b4.w};
            #pragma unroll
            for (int mb = 0; mb < 4; ++mb){
                const int mg = m0 + wm + mb*16 + c16;
                const int bi = mg >> 11, s = mg & (SS - 1);
                const f32x4 av = acc[na*4 + mb];
                ushort4 hv;
                ushort_t* hp = &hv.x;
                #pragma unroll
                for (int r = 0; r < 4; ++r)
                    hp[r] = f2bf((av[r] + bb[r]) * tsc);
                *(ushort4*)&OutH[(((size_t)(bi * HH + h)) * SS + s) * DH + d0] = hv;
            }
        }
    } else { // MODE 2: V^T hi only
        #pragma unroll
        for (int ma = 0; ma < 4; ++ma){
            const int mg = m0 + wm + ma*16 + qd*4;
            const int bi = mg >> 11, s0 = mg & (SS - 1);
            #pragma unroll
            for (int nb = 0; nb < 2; ++nb){
                const int ng = n0 + wn + nb*16 + c16;
                const int h = ng >> 6, d = ng & 63;
                const float bv = bias[ng];
                const f32x4 av = acc[ma*2 + nb];
                ushort4 hv;
                ushort_t* hp = &hv.x;
                #pragma unroll
                for (int r = 0; r < 4; ++r) hp[r] = f2bf(av[r] + bv);
                *(ushort4*)&OutH[(((size_t)(bi * HH + h)) * DH + d) * SS + s0] = hv;
            }
        }
    }
}

// XCD-panel swizzle (bijective for 16x32 grids; kept from R7, harmless).
__device__ __forceinline__ void panel_swizzle(int& bx, int& by){
    const int lin = blockIdx.x + 16 * blockIdx.y;   // 0..511
    const int xcd = lin & 7, idx = lin >> 3;        // idx 0..63
    bx = idx & 15;
    by = (xcd << 2) | (idx >> 4);
}

// Fused Q/K/V projections: blockIdx.z picks the problem. 1536 blocks.
__global__ __launch_bounds__(256) void gemm_qkv(
        const ushort_t* __restrict__ Xqh, const ushort_t* __restrict__ Xql,
        const ushort_t* __restrict__ Xkh, const ushort_t* __restrict__ Xkl,
        const ushort_t* __restrict__ Xvh, const ushort_t* __restrict__ Xvl,
        const ushort_t* __restrict__ Wqh, const ushort_t* __restrict__ Wql,
        const ushort_t* __restrict__ Wkh, const ushort_t* __restrict__ Wkl,
        const ushort_t* __restrict__ Wvh, const ushort_t* __restrict__ Wvl,
        const float* __restrict__ bq, const float* __restrict__ bk,
        const float* __restrict__ bv, const float* __restrict__ ts,
        ushort_t* __restrict__ Qh, ushort_t* __restrict__ Ql,
        ushort_t* __restrict__ Kh, ushort_t* __restrict__ Vth)
{
    __shared__ ushort_t buf[12288];   // 24 KB
    int bx, by;
    panel_swizzle(bx, by);
    const int z = blockIdx.z;
    if (z == 0)
        gemm_body<0>(Xqh, Xql, Wqh, Wql, bq, nullptr, nullptr, Qh, Ql, buf, bx, by);
    else if (z == 1)
        gemm_body<1>(Xkh, Xkl, Wkh, Wkl, bk, ts, nullptr, Kh, nullptr, buf, bx, by);
    else
        gemm_body<2>(Xvh, Xvl, Wvh, Wvl, bv, nullptr, nullptr, Vth, nullptr, buf, bx, by);
}

__global__ __launch_bounds__(256) void gemm_out(
        const ushort_t* __restrict__ AOh, const ushort_t* __restrict__ AOl,
        const ushort_t* __restrict__ Wth, const ushort_t* __restrict__ Wtl,
        const float* __restrict__ bias, float* __restrict__ OutF)
{
    __shared__ ushort_t buf[12288];
    int bx, by;
    panel_swizzle(bx, by);
    gemm_body<3>(AOh, AOl, Wth, Wtl, bias, nullptr, OutF, nullptr, nullptr, buf, bx, by);
}

// ---------------------------------------------------------------------------
// Fused attention (R7 structure, frozen). Output written as split bf16 hi/lo
// so gemm_out can stage it via global_load_lds (epilogue split = ~6 VALU +
// one extra 4B store per thread; R4-verified numerics).
// ---------------------------------------------------------------------------
__global__ __launch_bounds__(512, 4) void attn_kernel(
        const ushort_t* __restrict__ Qh, const ushort_t* __restrict__ Ql,
        const ushort_t* __restrict__ Khi, const ushort_t* __restrict__ Vth,
        ushort_t* __restrict__ AOh, ushort_t* __restrict__ AOl)
{
    __shared__ __align__(16) char uni[65536];
    __shared__ float wsums[8][16];
    __shared__ unsigned thr16[16];

    const int tid  = threadIdx.x;
    const int lane = tid & 63;
    const int wave = tid >> 6;
    const int qd   = lane >> 4;
    const int c16  = lane & 15;
    const unsigned Bx = blockIdx.x;
    const int xcd  = Bx & 7;
    const int qq   = Bx >> 3;
    const int tile = qq & 127;
    const int bh   = (qq >> 7) * 8 + xcd;
    const int t0   = tile * QT;
    const int wbase = wave * 256;

    // ---- Q fragments (pre-split hi/lo) ----
    bf16x8 qh[2], ql[2];
    {
        const size_t qbase = ((size_t)bh * SS + t0 + c16) * DH;
        #pragma unroll
        for (int kc = 0; kc < 2; ++kc){
            qh[kc] = *(const bf16x8*)&Qh[qbase + kc*32 + qd*8];
            ql[kc] = *(const bf16x8*)&Ql[qbase + kc*32 + qd*8];
        }
    }

    // ---- phase 1: scores (K hi-only, Q split) ----
    f32x4 acc[16];
    const ushort_t* Kh = Khi + (size_t)bh * SS * DH;
    #pragma unroll
    for (int t = 0; t < 16; ++t){
        f32x4 a = {0.f, 0.f, 0.f, 0.f};
        const int srow = wbase + t*16 + c16;
        const ushort_t* kp = Kh + (size_t)srow * DH + qd*8;
        #pragma unroll
        for (int kc = 0; kc < 2; ++kc){
            bf16x8 kh = *(const bf16x8*)(kp + kc*32);
            a = __builtin_amdgcn_mfma_f32_16x16x32_bf16(qh[kc], kh, a, 0, 0, 0);
            a = __builtin_amdgcn_mfma_f32_16x16x32_bf16(ql[kc], kh, a, 0, 0, 0);
        }
        acc[t] = a;
    }

    // ---- scale + diag boost, to sortkeys in place ----
    #pragma unroll
    for (int t = 0; t < 16; ++t){
        const int colg = wbase + t*16 + c16;
        #pragma unroll
        for (int r = 0; r < 4; ++r){
            float v = acc[t][r] * 0.15625f;        // 1/8 * 1.25
            if (colg == t0 + qd*4 + r) v *= 1.15f;
            acc[t][r] = __uint_as_float(sortkey(v));
        }
    }

    // ---- phase 2: exact top-k threshold (exchange + bisection) ----
    float* ex = (float*)uni;   // 8 rows x 2048 fp32 (key bits)
    #pragma unroll
    for (int half = 0; half < 2; ++half){
        if ((qd >> 1) == half){
            const int rl = (qd & 1) * 4;
            #pragma unroll
            for (int t = 0; t < 16; ++t)
                #pragma unroll
                for (int r = 0; r < 4; ++r)
                    ex[(rl + r) * SS + wbase + t*16 + c16] = acc[t][r];
        }
        __syncthreads();
        unsigned cand[32];
        #pragma unroll
        for (int j = 0; j < 32; ++j)
            cand[j] = __float_as_uint(ex[wave * SS + lane + 64*j]);
        // measured bracket: min/max key over the row (sortkey is monotone)
        unsigned kmn = cand[0], kmx = cand[0];
        #pragma unroll
        for (int j = 1; j < 32; ++j){
            kmn = (cand[j] < kmn) ? cand[j] : kmn;
            kmx = (cand[j] > kmx) ? cand[j] : kmx;
        }
        #pragma unroll
        for (int off = 1; off < 64; off <<= 1){
            const unsigned on = (unsigned)__shfl_xor((int)kmn, off, 64);
            const unsigned ox = (unsigned)__shfl_xor((int)kmx, off, 64);
            kmn = (on < kmn) ? on : kmn;
            kmx = (ox > kmx) ? ox : kmx;
        }
        unsigned lo = kmn, hi = kmx + 1u;   // cnt(lo)=2048>=K, cnt(hi)=0<K
        #pragma unroll 1
        for (int it = 0; it < 32 && (hi - lo) > 1u; ++it){
            const unsigned mid = lo + ((hi - lo) >> 1);
            int c = 0;
            #pragma unroll
            for (int j = 0; j < 32; ++j){
                int pc;
                asm("v_cmp_le_u32 vcc, %1, %2\n\t"
                    "s_bcnt1_i32_b64 %0, vcc"
                    : "=s"(pc) : "s"(mid), "v"(cand[j]) : "vcc");
                c += pc;
            }
            if (c == KKSEL){ lo = mid; break; }
            if (c > KKSEL) lo = mid; else hi = mid;
        }
        if (lane == 0) thr16[half*8 + wave] = lo;
        __syncthreads();
    }

    // ---- phase 3: boost + exp + row sums ----
    unsigned thr[4];
    #pragma unroll
    for (int r = 0; r < 4; ++r) thr[r] = thr16[qd*4 + r];
    float psum[4] = {0.f, 0.f, 0.f, 0.f};
    #pragma unroll
    for (int t = 0; t < 16; ++t){
        #pragma unroll
        for (int r = 0; r < 4; ++r){
            const unsigned key = __float_as_uint(acc[t][r]);
            float s = inv_sortkey(key);
            s *= (key >= thr[r]) ? 1.15f : 1.0f;
            const float e = __expf(s);
            acc[t][r] = e;
            psum[r] += e;
        }
    }
    #pragma unroll
    for (int off = 1; off <= 8; off <<= 1){
        #pragma unroll
        for (int r = 0; r < 4; ++r) psum[r] += __shfl_xor(psum[r], off, 64);
    }
    if (c16 == 0){
        #pragma unroll
        for (int r = 0; r < 4; ++r) wsums[wave][qd*4 + r] = psum[r];
    }
    __syncthreads();
    float pinv[4];
    #pragma unroll
    for (int r = 0; r < 4; ++r){
        const int row = qd*4 + r;
        float s = 0.f;
        #pragma unroll
        for (int w = 0; w < 8; ++w) s += wsums[w][row];
        pinv[r] = 1.f / s;
    }

    // ---- phase 4: O = P @ V (two 128-col halves per wave) ----
    const ushort_t* Vh = Vth + (size_t)bh * DH * SS;
    ushort_t* pw = (ushort_t*)uni + wave * (QT * PST);   // per-wave region
    f32x4 oacc[4];
    #pragma unroll
    for (int dt = 0; dt < 4; ++dt) oacc[dt] = (f32x4){0.f, 0.f, 0.f, 0.f};

    #pragma unroll
    for (int half = 0; half < 2; ++half){
        #pragma unroll
        for (int tt = 0; tt < 8; ++tt){
            const int t = half*8 + tt;
            #pragma unroll
            for (int r = 0; r < 4; ++r)
                pw[(qd*4 + r) * PST + tt*16 + c16] = f2bf(acc[t][r] * pinv[r]);
        }
        // per-wave region: same-wave ds_write -> ds_read, no barrier needed
        #pragma unroll
        for (int kc = 0; kc < 4; ++kc){
            bf16x8 pf = *(const bf16x8*)&pw[c16 * PST + kc*32 + qd*8];
            const int sbase = wbase + half*128 + kc*32 + qd*8;
            #pragma unroll
            for (int dt = 0; dt < 4; ++dt){
                const int d = dt*16 + c16;
                bf16x8 vh = *(const bf16x8*)(Vh + (size_t)d * SS + sbase);
                oacc[dt] = __builtin_amdgcn_mfma_f32_16x16x32_bf16(pf, vh, oacc[dt], 0, 0, 0);
            }
        }
    }

    // ---- cross-wave O reduction + split bf16 store ----
    __syncthreads();   // all probs reads done before red overwrites the union
    float* red = (float*)uni;   // 8 x 16 x 65
    #pragma unroll
    for (int dt = 0; dt < 4; ++dt)
        #pragma unroll
        for (int r = 0; r < 4; ++r)
            red[(wave*16 + qd*4 + r) * 65 + dt*16 + c16] = oacc[dt][r];
    __syncthreads();

    const int b = bh >> 4, h = bh & 15;
    {
        const int r  = tid >> 5;           // 0..15
        const int c2 = (tid & 31) * 2;     // 0,2,..,62
        float s0 = 0.f, s1 = 0.f;
        #pragma unroll
        for (int w = 0; w < 8; ++w){
            s0 += red[(w*16 + r) * 65 + c2];
            s1 += red[(w*16 + r) * 65 + c2 + 1];
        }
        const size_t o = ((size_t)b * SS + t0 + r) * EE + h*DH + c2;
        ushort2 hv, lv;
        hv.x = f2bf(s0); lv.x = f2bf(s0 - bf2f(hv.x));
        hv.y = f2bf(s1); lv.y = f2bf(s1 - bf2f(hv.y));
        *(ushort2*)&AOh[o] = hv;
        *(ushort2*)&AOl[o] = lv;
    }
}

// ---------------------------------------------------------------------------
extern "C" void kernel_launch(void* const* d_in, const int* in_sizes, int n_in,
                              void* d_out, int out_size, void* d_ws, size_t ws_size,
                              hipStream_t stream)
{
    const float* query = (const float*)d_in[0];
    const float* key   = (const float*)d_in[1];
    const float* value = (const float*)d_in[2];
    const float* Wq    = (const float*)d_in[3];
    const float* bq    = (const float*)d_in[4];
    const float* Wk    = (const float*)d_in[5];
    const float* bk    = (const float*)d_in[6];
    const float* Wv    = (const float*)d_in[7];
    const float* bv    = (const float*)d_in[8];
    const float* Wo    = (const float*)d_in[9];
    const float* bo    = (const float*)d_in[10];
    const float* ts    = (const float*)d_in[11];
    float* out = (float*)d_out;
    char* w = (char*)d_ws;

    const size_t MB = 1u << 20;
    // 0-32: attention operand buffers (outputs of gemm_qkv)
    ushort_t* Qh  = (ushort_t*)(w + 0 * MB);
    ushort_t* Ql  = (ushort_t*)(w + 8 * MB);
    ushort_t* Kh  = (ushort_t*)(w + 16 * MB);
    ushort_t* Vth = (ushort_t*)(w + 24 * MB);
    // 32-48: converted weights (2 MB each)
    ushort_t* Wqh = (ushort_t*)(w + 32 * MB);
    ushort_t* Wql = (ushort_t*)(w + 34 * MB);
    ushort_t* Wkh = (ushort_t*)(w + 36 * MB);
    ushort_t* Wkl = (ushort_t*)(w + 38 * MB);
    ushort_t* Wvh = (ushort_t*)(w + 40 * MB);
    ushort_t* Wvl = (ushort_t*)(w + 42 * MB);
    ushort_t* Woh = (ushort_t*)(w + 44 * MB);
    ushort_t* Wol = (ushort_t*)(w + 46 * MB);
    // 48-96: pre-split activations (8 MB each)
    ushort_t* Xqh = (ushort_t*)(w + 48 * MB);
    ushort_t* Xql = (ushort_t*)(w + 56 * MB);
    ushort_t* Xkh = (ushort_t*)(w + 64 * MB);
    ushort_t* Xkl = (ushort_t*)(w + 72 * MB);
    ushort_t* Xvh = (ushort_t*)(w + 80 * MB);
    ushort_t* Xvl = (ushort_t*)(w + 88 * MB);
    // attn output overlays the Xq region (dead after gemm_qkv, stream-ordered)
    ushort_t* AOh = (ushort_t*)(w + 48 * MB);
    ushort_t* AOl = (ushort_t*)(w + 56 * MB);

    CvtArgs ca;
    ca.W[0] = Wq;  ca.W[1] = Wk;  ca.W[2] = Wv;  ca.W[3] = Wo;
    ca.H[0] = Wqh; ca.H[1] = Wkh; ca.H[2] = Wvh; ca.H[3] = Woh;
    ca.L[0] = Wql; ca.L[1] = Wkl; ca.L[2] = Wvl; ca.L[3] = Wol;

    CvtX cx;
    cx.X[0] = query; cx.X[1] = key; cx.X[2] = value;
    cx.H[0] = Xqh;   cx.H[1] = Xkh; cx.H[2] = Xvh;
    cx.L[0] = Xql;   cx.L[1] = Xkl; cx.L[2] = Xvl;

    hipLaunchKernelGGL(convert_wt4, dim3(16, 16, 4), dim3(256), 0, stream, ca);
    hipLaunchKernelGGL(convert_x3, dim3(2048, 1, 3), dim3(256), 0, stream, cx);
    // 128x64 tiles: 16 x 32 x 3 = 1536 blocks
    hipLaunchKernelGGL(gemm_qkv, dim3(16, 32, 3), dim3(256), 0, stream,
                       Xqh, Xql, Xkh, Xkl, Xvh, Xvl,
                       Wqh, Wql, Wkh, Wkl, Wvh, Wvl,
                       bq, bk, bv, ts, Qh, Ql, Kh, Vth);
    hipLaunchKernelGGL(attn_kernel, dim3(BB * HH * (SS / QT)), dim3(512), 0, stream,
                       Qh, Ql, Kh, Vth, AOh, AOl);
    hipLaunchKernelGGL(gemm_out, dim3(16, 32), dim3(256), 0, stream,
                       AOh, AOl, Woh, Wol, bo, out);
}